// Round 1
// baseline (106.840 us; speedup 1.0000x reference)
//
#include <hip/hip_runtime.h>
#include <hip/hip_bf16.h>

// loss = 0.5 * ( sum_j[(y-mu)^2/sigma + log(sigma)] + NT*log(2pi) ) / (NT*BS)
// computed over the LAST row only (the torch loop overwrites `loss` each
// iteration, so only sample bs-1 survives).

#define LOG_2PI 1.8378770664093453f

__global__ __launch_bounds__(256) void criterion_lastrow_kernel(
    const float* __restrict__ mu,
    const float* __restrict__ sigma,
    const float* __restrict__ y,
    float* __restrict__ out,
    int nt, int bs)
{
    const long long base = (long long)(bs - 1) * (long long)nt;
    const int tid = threadIdx.x;

    float acc = 0.0f;
    for (int j = tid; j < nt; j += 256) {
        float m = mu[base + j];
        float s = sigma[base + j];
        float t = y[base + j];
        float d = t - m;
        acc += d * d / s + __logf(s) * 0.0f + logf(s);  // use precise logf
    }

    // wave (64-lane) reduction
    #pragma unroll
    for (int off = 32; off > 0; off >>= 1)
        acc += __shfl_down(acc, off, 64);

    __shared__ float wsum[4];
    const int wave = tid >> 6;
    const int lane = tid & 63;
    if (lane == 0) wsum[wave] = acc;
    __syncthreads();

    if (tid == 0) {
        float total = wsum[0] + wsum[1] + wsum[2] + wsum[3];
        float logprob_neg = 0.5f * (total + (float)nt * LOG_2PI);
        out[0] = logprob_neg / ((float)nt * (float)bs);
    }
}

extern "C" void kernel_launch(void* const* d_in, const int* in_sizes, int n_in,
                              void* d_out, int out_size, void* d_ws, size_t ws_size,
                              hipStream_t stream) {
    const float* mu    = (const float*)d_in[0];
    const float* sigma = (const float*)d_in[1];
    const float* y     = (const float*)d_in[2];
    float* out = (float*)d_out;

    const int nt = 2048;
    const int bs = in_sizes[0] / nt;   // 4096

    criterion_lastrow_kernel<<<1, 256, 0, stream>>>(mu, sigma, y, out, nt, bs);
}